// Round 7
// baseline (267.550 us; speedup 1.0000x reference)
//
#include <hip/hip_runtime.h>

#define NV  16
#define NB  64
#define NT  256
#define NH  128
#define NFC 256
#define NC  10

typedef _Float16 half8  __attribute__((ext_vector_type(8)));
typedef float    f32x4  __attribute__((ext_vector_type(4)));

// One workgroup = one variable v, EIGHT batch rows as TWO independent 4-row
// chains (A: b0..b0+3, B: b0+4..b0+7). 8 waves, 128 WGs.
// Both chains advance one step per barrier period; their instruction streams
// are independent between barriers, so chain B's issue hides chain A's
// ds_read / MFMA / transcendental latencies (the round-5/6 lockstep convoy
// was chain-bound at ~1100 cyc/step with no independent work to overlap).
// Per chain per step: gh^T = Whh(384n x 128k) * h^T(128k x 16b), mfma
// 16x16x32 f16, B slots n,n+4,n+8,n+12 duplicate row n&3 (4x ds_write_b16),
// so every lane owns the full gh for its row rb = l&3 in its own acc; col
// pick s = (l>>2)&3 via cndmask tree — zero cross-lane ops (verified r5/r6).
// A-fragments, C-init biases, Wih scalars are SHARED between the chains
// (same v, same j) — only h_old/x/frag buffers are per-chain.
// C layout (verified r2): col(B slot) = lane&15, row(h-col) = (lane>>4)*4+reg.
// Activation algebra (prescaled, division-minimized, verified r2-r6):
//   r = rcp(1+exp2(srs)); a = exp2(szs); b = exp2(-ccs)
//   h' = [a(1-b) + h(1+b)] / [(1+a)(1+b)] ; num = fma(b, h-a, a+h)
// bih of r/z folded into MFMA C-init; n-gate bih outside the r-multiply.
__global__ __launch_bounds__(512, 2) void gru_scan_kernel(
    const float* __restrict__ x,   const float* __restrict__ Wih,
    const float* __restrict__ Whh, const float* __restrict__ bih,
    const float* __restrict__ bhh, const float* __restrict__ Wp,
    const float* __restrict__ bp,  float* __restrict__ concat_ws)
{
    __shared__ __align__(16) _Float16 fragA[2][2048];  // [kb*512 + slot*8 + e]
    __shared__ __align__(16) _Float16 fragB[2][2048];
    __shared__ float xT[NT][9];                        // 8 rows, padded
    __shared__ float pc[8][8];

    const int tid = threadIdx.x;
    const int w   = tid >> 6;        // wave 0..7
    const int l   = tid & 63;
    const int r   = l & 15;          // A-fragment gate-col index
    const int m4  = l >> 4;          // 0..3
    const int rb  = l & 3;           // batch row within chunk
    const int s   = (l >> 2) & 3;    // col selector
    const int bid = blockIdx.x;
    const int v   = bid >> 3;        // variable
    const int b0  = (bid & 7) << 3;  // 8-row base; A rows b0+0..3, B rows b0+4..7
    const int j0  = (w << 4) + (m4 << 2);
    const int j   = j0 + s;

    constexpr float L2E = 1.44269504088896340736f;
    const float SCL0 = -L2E, SCL2 = 2.0f * L2E;

    // ---- stage x[v, b0+rr, :] into xT[t][rr], rr = 0..7 (r5-verified) ----
    {
        const int rr = tid >> 6;          // 0..7
        const int t0 = (tid & 63) << 2;   // 0..252
        const float4 xv = *(const float4*)(x + (size_t)(v * NB + b0 + rr) * NT + t0);
        xT[t0][rr] = xv.x; xT[t0+1][rr] = xv.y; xT[t0+2][rr] = xv.z; xT[t0+3][rr] = xv.w;
    }
    // zero all frag buffers (h0 = 0)
    ((int4*)fragA)[tid] = int4{0, 0, 0, 0};
    ((int4*)fragB)[tid] = int4{0, 0, 0, 0};

    // ---- preload PRESCALED Whh A-fragments (shared by both chains) ----
    half8 afr[3][4];
    #pragma unroll
    for (int g = 0; g < 3; ++g) {
        const float sc = (g == 2) ? SCL2 : SCL0;
        #pragma unroll
        for (int kb = 0; kb < 4; ++kb) {
            const float* wpp = Whh + (size_t)(v * 384 + g * 128 + (w << 4) + r) * 128
                             + kb * 32 + m4 * 8;
            float4 lo = *(const float4*)wpp;
            float4 hi = *(const float4*)(wpp + 4);
            half8 hf;
            hf[0]=(_Float16)(sc*lo.x); hf[1]=(_Float16)(sc*lo.y);
            hf[2]=(_Float16)(sc*lo.z); hf[3]=(_Float16)(sc*lo.w);
            hf[4]=(_Float16)(sc*hi.x); hf[5]=(_Float16)(sc*hi.y);
            hf[6]=(_Float16)(sc*hi.z); hf[7]=(_Float16)(sc*hi.w);
            afr[g][kb] = hf;
        }
    }

    // MFMA C-init (shared): r/z get prescaled (bhh+bih); n gets bhh only
    f32x4 c0i, c1i, c2i;
    #pragma unroll
    for (int q = 0; q < 4; ++q) {
        const int i0 = v * 384 + j0 + q;
        c0i[q] = SCL0 * (bhh[i0] + bih[i0]);
        c1i[q] = SCL0 * (bhh[i0 + 128] + bih[i0 + 128]);
        c2i[q] = SCL2 * bhh[i0 + 256];
    }
    // handler params for col j (shared)
    const int ih = v * 384 + j;
    const float wih0 = SCL0 * Wih[ih];
    const float wih1 = SCL0 * Wih[ih + 128];
    const float wihn = SCL2 * Wih[ih + 256];
    const float bihn = SCL2 * bih[ih + 256];
    const float wpj  = Wp[v * NH + j];

    float h_oldA = 0.f, h_oldB = 0.f;

    const int fwoff = (j >> 5) * 512 + (rb + 16 * ((j & 31) >> 3)) * 8 + (j & 7);
    const int rdoff = l * 8;

    __syncthreads();

    // one barrier period = one step of BOTH chains
    auto period = [&](const _Float16* __restrict__ fbA, _Float16* __restrict__ fwA,
                      const _Float16* __restrict__ fbB, _Float16* __restrict__ fwB,
                      const float xrA, const float xrB) {
        half8 bfrA[4], bfrB[4];
        #pragma unroll
        for (int kb = 0; kb < 4; ++kb) {
            bfrA[kb] = *(const half8*)(fbA + kb * 512 + rdoff);
            bfrB[kb] = *(const half8*)(fbB + kb * 512 + rdoff);
        }

        f32x4 aA0 = __builtin_amdgcn_mfma_f32_16x16x32_f16(afr[0][0], bfrA[0], c0i, 0, 0, 0);
        f32x4 aA1 = __builtin_amdgcn_mfma_f32_16x16x32_f16(afr[1][0], bfrA[0], c1i, 0, 0, 0);
        f32x4 aA2 = __builtin_amdgcn_mfma_f32_16x16x32_f16(afr[2][0], bfrA[0], c2i, 0, 0, 0);
        f32x4 aB0 = __builtin_amdgcn_mfma_f32_16x16x32_f16(afr[0][0], bfrB[0], c0i, 0, 0, 0);
        f32x4 aB1 = __builtin_amdgcn_mfma_f32_16x16x32_f16(afr[1][0], bfrB[0], c1i, 0, 0, 0);
        f32x4 aB2 = __builtin_amdgcn_mfma_f32_16x16x32_f16(afr[2][0], bfrB[0], c2i, 0, 0, 0);
        #pragma unroll
        for (int kb = 1; kb < 4; ++kb) {
            aA0 = __builtin_amdgcn_mfma_f32_16x16x32_f16(afr[0][kb], bfrA[kb], aA0, 0, 0, 0);
            aA1 = __builtin_amdgcn_mfma_f32_16x16x32_f16(afr[1][kb], bfrA[kb], aA1, 0, 0, 0);
            aA2 = __builtin_amdgcn_mfma_f32_16x16x32_f16(afr[2][kb], bfrA[kb], aA2, 0, 0, 0);
            aB0 = __builtin_amdgcn_mfma_f32_16x16x32_f16(afr[0][kb], bfrB[kb], aB0, 0, 0, 0);
            aB1 = __builtin_amdgcn_mfma_f32_16x16x32_f16(afr[1][kb], bfrB[kb], aB1, 0, 0, 0);
            aB2 = __builtin_amdgcn_mfma_f32_16x16x32_f16(afr[2][kb], bfrB[kb], aB2, 0, 0, 0);
        }

        const bool s1 = (s & 1) != 0, s2 = (s & 2) != 0;
        const float gA0 = s2 ? (s1 ? aA0[3] : aA0[2]) : (s1 ? aA0[1] : aA0[0]);
        const float gA1 = s2 ? (s1 ? aA1[3] : aA1[2]) : (s1 ? aA1[1] : aA1[0]);
        const float gA2 = s2 ? (s1 ? aA2[3] : aA2[2]) : (s1 ? aA2[1] : aA2[0]);
        const float gB0 = s2 ? (s1 ? aB0[3] : aB0[2]) : (s1 ? aB0[1] : aB0[0]);
        const float gB1 = s2 ? (s1 ? aB1[3] : aB1[2]) : (s1 ? aB1[1] : aB1[0]);
        const float gB2 = s2 ? (s1 ? aB2[3] : aB2[2]) : (s1 ? aB2[1] : aB2[0]);

        // chain A activation
        const float srsA = fmaf(xrA, wih0, gA0);
        const float szsA = fmaf(xrA, wih1, gA1);
        const float gnsA = fmaf(xrA, wihn, bihn);
        // chain B activation (independent stream)
        const float srsB = fmaf(xrB, wih0, gB0);
        const float szsB = fmaf(xrB, wih1, gB1);
        const float gnsB = fmaf(xrB, wihn, bihn);

        const float rgA = __builtin_amdgcn_rcpf(1.f + __builtin_amdgcn_exp2f(srsA));
        const float rgB = __builtin_amdgcn_rcpf(1.f + __builtin_amdgcn_exp2f(srsB));
        const float aA  = __builtin_amdgcn_exp2f(szsA);
        const float aB  = __builtin_amdgcn_exp2f(szsB);
        const float ccA = fmaf(rgA, gA2, gnsA);
        const float ccB = fmaf(rgB, gB2, gnsB);
        const float bA  = __builtin_amdgcn_exp2f(-ccA);
        const float bB  = __builtin_amdgcn_exp2f(-ccB);

        const float numA = fmaf(bA, h_oldA - aA, aA + h_oldA);
        const float numB = fmaf(bB, h_oldB - aB, aB + h_oldB);
        const float denA = (1.f + aA) * (1.f + bA);
        const float denB = (1.f + aB) * (1.f + bB);
        const float hnA  = numA * __builtin_amdgcn_rcpf(denA);
        const float hnB  = numB * __builtin_amdgcn_rcpf(denB);
        h_oldA = hnA;
        h_oldB = hnB;
        const _Float16 hvA = (_Float16)hnA;
        const _Float16 hvB = (_Float16)hnB;
        fwA[fwoff]      = hvA;  fwB[fwoff]      = hvB;
        fwA[fwoff + 32] = hvA;  fwB[fwoff + 32] = hvB;
        fwA[fwoff + 64] = hvA;  fwB[fwoff + 64] = hvB;
        fwA[fwoff + 96] = hvA;  fwB[fwoff + 96] = hvB;
        __syncthreads();
    };

    for (int t = 0; t < NT; t += 2) {
        period(fragA[0], fragA[1], fragB[0], fragB[1], xT[t][rb],     xT[t][4 + rb]);
        period(fragA[1], fragA[0], fragB[1], fragB[0], xT[t + 1][rb], xT[t + 1][4 + rb]);
    }

    // ---- epilogue: concat[b0+rr][v] = sum_j h[rr][j]*Wp[v][j] + bp[v] ----
    float pA = h_oldA * wpj;
    float pB = h_oldB * wpj;
    pA += __shfl_xor(pA, 4, 64);  pB += __shfl_xor(pB, 4, 64);
    pA += __shfl_xor(pA, 8, 64);  pB += __shfl_xor(pB, 8, 64);
    pA += __shfl_xor(pA, 16, 64); pB += __shfl_xor(pB, 16, 64);
    pA += __shfl_xor(pA, 32, 64); pB += __shfl_xor(pB, 32, 64);
    if (l < 4) { pc[w][l] = pA; pc[w][4 + l] = pB; }
    __syncthreads();
    if (tid < 8) {
        float acc = bp[v];
        #pragma unroll
        for (int ww = 0; ww < 8; ++ww) acc += pc[ww][tid];
        concat_ws[(b0 + tid) * NV + v] = acc;
    }
}

// FC head: concat[64][16] -> relu(W1) -> W2 -> out[64][10]. One small block.
__global__ __launch_bounds__(256, 1) void fc_kernel(
    const float* __restrict__ cws, const float* __restrict__ W1,
    const float* __restrict__ b1,  const float* __restrict__ W2,
    const float* __restrict__ b2,  float* __restrict__ out)
{
    __shared__ float cc[NB][NV + 1];
    __shared__ float hfc[NB][NFC + 1];
    const int tid = threadIdx.x;
    for (int i = tid; i < NB * NV; i += 256) cc[i >> 4][i & 15] = cws[i];
    __syncthreads();

    float w1r[NV];
    #pragma unroll
    for (int q = 0; q < NV; q += 4) {
        float4 t4 = *(const float4*)(W1 + tid * NV + q);
        w1r[q] = t4.x; w1r[q+1] = t4.y; w1r[q+2] = t4.z; w1r[q+3] = t4.w;
    }
    const float bb = b1[tid];
    for (int b = 0; b < NB; ++b) {
        float sacc = bb;
        #pragma unroll
        for (int q = 0; q < NV; ++q) sacc = fmaf(cc[b][q], w1r[q], sacc);
        hfc[b][tid] = fmaxf(sacc, 0.f);
    }
    __syncthreads();

    for (int idx = tid; idx < NB * NC; idx += 256) {
        const int b = idx / NC, c = idx % NC;
        const float* w2r = W2 + c * NFC;
        float sacc = b2[c];
        #pragma unroll 4
        for (int f = 0; f < NFC; f += 4) {
            float4 wv = *(const float4*)(w2r + f);
            sacc = fmaf(hfc[b][f+0], wv.x, sacc);
            sacc = fmaf(hfc[b][f+1], wv.y, sacc);
            sacc = fmaf(hfc[b][f+2], wv.z, sacc);
            sacc = fmaf(hfc[b][f+3], wv.w, sacc);
        }
        out[idx] = sacc;
    }
}

extern "C" void kernel_launch(void* const* d_in, const int* in_sizes, int n_in,
                              void* d_out, int out_size, void* d_ws, size_t ws_size,
                              hipStream_t stream) {
    const float* x   = (const float*)d_in[0];
    const float* Wih = (const float*)d_in[1];
    const float* Whh = (const float*)d_in[2];
    const float* bih = (const float*)d_in[3];
    const float* bhh = (const float*)d_in[4];
    const float* Wp  = (const float*)d_in[5];
    const float* bp  = (const float*)d_in[6];
    const float* W1  = (const float*)d_in[7];
    const float* b1  = (const float*)d_in[8];
    const float* W2  = (const float*)d_in[9];
    const float* b2  = (const float*)d_in[10];
    float* out = (float*)d_out;
    float* cws = (float*)d_ws;  // concat scratch: 64*16 f32 = 4 KB

    gru_scan_kernel<<<dim3(128), dim3(512), 0, stream>>>(x, Wih, Whh, bih, bhh, Wp, bp, cws);
    fc_kernel<<<dim3(1), dim3(256), 0, stream>>>(cws, W1, b1, W2, b2, out);
}

// Round 9
// 261.668 us; speedup vs baseline: 1.0225x; 1.0225x over previous
//
#include <hip/hip_runtime.h>

#define NV  16
#define NB  64
#define NT  256
#define NH  128
#define NFC 256
#define NC  10

typedef _Float16 half8  __attribute__((ext_vector_type(8)));
typedef float    f32x4  __attribute__((ext_vector_type(4)));

// One workgroup = one variable v, TWO batch rows, 4 waves (256 thr).
// 512 WGs -> TWO independent WGs per CU: their barriers are decoupled, so
// one WG's issue phase hides the other's serial-chain stalls (r6/r7 showed a
// single lockstep WG per CU is chain-bound at ~1100 cyc/step regardless of
// per-step issue).
// Wave w4 owns h-cols [w4*32, w4*32+32) = 6 gate-tiles (3 gates x 2 ranges);
// A-frags (96 VGPRs, prescaled) resident; B-frag ds_read amortized over 24
// MFMAs. B slots n hold h[row n&1] (dup-8): every lane owns the full gh for
// its (row rb = n&1, col j) in its own acc -> zero cross-lane redistribution
// (r5/r6-verified trick): lane n = rb + 2*(q + 4*cr) picks acc[g][cr][q] via
// cndmask. h' written to the 8 dup slots as 8x ds_write_b16 (stride 32B).
// C layout (verified r2): col(B slot) = lane&15, row = (lane>>4)*4 + reg.
// Activation algebra (prescaled, division-minimized, verified r2-r6):
//   r = rcp(1+exp2(srs)); a = exp2(szs); b = exp2(-ccs)
//   h' = [a(1-b) + h(1+b)] / [(1+a)(1+b)] ; num = fma(b, h-a, a+h)
// bih of r/z folded into MFMA C-init; n-gate bih outside the r-multiply.
__global__ __launch_bounds__(256, 2) void gru_scan_kernel(
    const float* __restrict__ x,   const float* __restrict__ Wih,
    const float* __restrict__ Whh, const float* __restrict__ bih,
    const float* __restrict__ bhh, const float* __restrict__ Wp,
    const float* __restrict__ bp,  float* __restrict__ concat_ws)
{
    __shared__ __align__(16) _Float16 frag[2][2048];  // 2 x 4KB: [kb*512 + slot*8]
    __shared__ float xT[NT][3];                       // x transposed, 2 rows padded
    __shared__ float pc[4][2];

    const int tid = threadIdx.x;
    const int w4  = tid >> 6;        // wave 0..3
    const int l   = tid & 63;
    const int n   = l & 15;          // B-slot / A-row index
    const int m4  = l >> 4;          // 0..3 (k-subgroup / C-row group)
    const int rb  = n & 1;           // this lane's batch row (0..1)
    const int s   = n >> 1;          // 0..7
    const int q   = s & 3;           // C-reg selector
    const int cr  = s >> 2;          // col-range selector (0..1)
    const int bid = blockIdx.x;
    const int v   = bid >> 5;        // variable
    const int b0  = (bid & 31) << 1; // batch base (2 rows)
    const int j   = (w4 << 5) + (cr << 4) + (m4 << 2) + q;  // this lane's h-col

    constexpr float L2E = 1.44269504088896340736f;
    const float SCL0 = -L2E, SCL2 = 2.0f * L2E;

    // ---- stage x[v, b0+rr, :] into xT[t][rr] ----
    {
        const int rr = tid >> 7;          // 0..1
        const int t0 = (tid & 127) << 1;  // 0..254
        const float2 xv = *(const float2*)(x + (size_t)(v * NB + b0 + rr) * NT + t0);
        xT[t0][rr] = xv.x; xT[t0 + 1][rr] = xv.y;
    }
    // zero BOTH frag buffers (h0 = 0)
    ((int4*)frag)[tid]       = int4{0, 0, 0, 0};
    ((int4*)frag)[tid + 256] = int4{0, 0, 0, 0};

    // ---- preload PRESCALED Whh A-fragments for 6 tiles (g, cr_) ----
    // tile gate-rows: g*128 + w4*32 + cr_*16 + (0..15); A[n][k], lane = n+16*m4
    half8 afr[3][2][4];
    #pragma unroll
    for (int g = 0; g < 3; ++g) {
        const float sc = (g == 2) ? SCL2 : SCL0;
        #pragma unroll
        for (int c2 = 0; c2 < 2; ++c2) {
            #pragma unroll
            for (int kb = 0; kb < 4; ++kb) {
                const float* wpp = Whh
                    + (size_t)(v * 384 + g * 128 + (w4 << 5) + (c2 << 4) + n) * 128
                    + kb * 32 + m4 * 8;
                float4 lo = *(const float4*)wpp;
                float4 hi = *(const float4*)(wpp + 4);
                half8 hf;
                hf[0]=(_Float16)(sc*lo.x); hf[1]=(_Float16)(sc*lo.y);
                hf[2]=(_Float16)(sc*lo.z); hf[3]=(_Float16)(sc*lo.w);
                hf[4]=(_Float16)(sc*hi.x); hf[5]=(_Float16)(sc*hi.y);
                hf[6]=(_Float16)(sc*hi.z); hf[7]=(_Float16)(sc*hi.w);
                afr[g][c2][kb] = hf;
            }
        }
    }

    // MFMA C-init per tile: rows m4*4+reg of cols range (w4, c2)
    //   r/z: prescaled (bhh + bih); n: prescaled bhh only
    f32x4 cini[3][2];
    #pragma unroll
    for (int g = 0; g < 3; ++g) {
        const float sc = (g == 2) ? SCL2 : SCL0;
        #pragma unroll
        for (int c2 = 0; c2 < 2; ++c2) {
            #pragma unroll
            for (int reg = 0; reg < 4; ++reg) {
                const int i0 = v * 384 + g * 128 + (w4 << 5) + (c2 << 4) + (m4 << 2) + reg;
                float bsum = bhh[i0];
                if (g < 2) bsum += bih[i0];
                cini[g][c2][reg] = sc * bsum;
            }
        }
    }
    // handler params for col j
    const int ih = v * 384 + j;
    const float wih0 = SCL0 * Wih[ih];
    const float wih1 = SCL0 * Wih[ih + 128];
    const float wihn = SCL2 * Wih[ih + 256];
    const float bihn = SCL2 * bih[ih + 256];
    const float wpj  = Wp[v * NH + j];

    float h_old = 0.f;

    // write base for (row rb, col j) -> 8 dup slots n' = rb+2i at +i*16 halfs.
    // element (n', j): (j>>5)*512 + (n' + 16*((j&31)>>3))*8 + (j&7)
    //   j>>5 = w4; (j&31)>>3 = cr*2 + (m4>>1); j&7 = (m4&1)*4 + q
    const int fwbase = (w4 << 9) + (rb + 16 * ((cr << 1) + (m4 >> 1))) * 8
                     + ((m4 & 1) << 2) + q;
    const int rdoff = l * 8;

    __syncthreads();

    auto step = [&](const _Float16* __restrict__ fb, _Float16* __restrict__ fwb,
                    const float xr) {
        half8 bfr[4];
        #pragma unroll
        for (int kb = 0; kb < 4; ++kb)
            bfr[kb] = *(const half8*)(fb + kb * 512 + rdoff);

        f32x4 aa[3][2];
        #pragma unroll
        for (int g = 0; g < 3; ++g)
            #pragma unroll
            for (int c2 = 0; c2 < 2; ++c2)
                aa[g][c2] = __builtin_amdgcn_mfma_f32_16x16x32_f16(
                                afr[g][c2][0], bfr[0], cini[g][c2], 0, 0, 0);
        #pragma unroll
        for (int kb = 1; kb < 4; ++kb)
            #pragma unroll
            for (int g = 0; g < 3; ++g)
                #pragma unroll
                for (int c2 = 0; c2 < 2; ++c2)
                    aa[g][c2] = __builtin_amdgcn_mfma_f32_16x16x32_f16(
                                    afr[g][c2][kb], bfr[kb], aa[g][c2], 0, 0, 0);

        // local pick: acc[g][cr][q] via cndmask (zero cross-lane)
        const bool q1 = (q & 1) != 0, q2 = (q & 2) != 0;
        float gv[3];
        #pragma unroll
        for (int g = 0; g < 3; ++g) {
            const f32x4 t = cr ? aa[g][1] : aa[g][0];
            gv[g] = q2 ? (q1 ? t[3] : t[2]) : (q1 ? t[1] : t[0]);
        }

        const float srs = fmaf(xr, wih0, gv[0]);
        const float szs = fmaf(xr, wih1, gv[1]);
        const float gns = fmaf(xr, wihn, bihn);
        const float rg  = __builtin_amdgcn_rcpf(1.f + __builtin_amdgcn_exp2f(srs));
        const float a   = __builtin_amdgcn_exp2f(szs);
        const float ccs = fmaf(rg, gv[2], gns);
        const float b   = __builtin_amdgcn_exp2f(-ccs);
        const float h   = h_old;
        const float num = fmaf(b, h - a, a + h);   // a(1-b) + h(1+b)
        const float den = (1.f + a) * (1.f + b);
        const float hn  = num * __builtin_amdgcn_rcpf(den);
        h_old = hn;
        const _Float16 hv = (_Float16)hn;
        #pragma unroll
        for (int i = 0; i < 8; ++i)
            fwb[fwbase + i * 16] = hv;   // dup slots rb, rb+2, .., rb+14
        __syncthreads();
    };

    for (int t = 0; t < NT; t += 2) {
        const float xa = xT[t][rb];
        const float xb = xT[t + 1][rb];
        step(&frag[0][0], &frag[1][0], xa);
        step(&frag[1][0], &frag[0][0], xb);
    }

    // ---- epilogue: concat[b0+rb][v] = sum_j h[rb][j]*Wp[v][j] + bp[v] ----
    float partial = h_old * wpj;
    partial += __shfl_xor(partial, 2, 64);
    partial += __shfl_xor(partial, 4, 64);
    partial += __shfl_xor(partial, 8, 64);
    partial += __shfl_xor(partial, 16, 64);
    partial += __shfl_xor(partial, 32, 64);
    if (l < 2) pc[w4][l] = partial;       // lane 0: rb=0, lane 1: rb=1
    __syncthreads();
    if (tid < 2) {
        float acc = bp[v];
        #pragma unroll
        for (int ww = 0; ww < 4; ++ww) acc += pc[ww][tid];
        concat_ws[(b0 + tid) * NV + v] = acc;
    }
}

// FC head: concat[64][16] -> relu(W1) -> W2 -> out[64][10]. One small block.
__global__ __launch_bounds__(256, 1) void fc_kernel(
    const float* __restrict__ cws, const float* __restrict__ W1,
    const float* __restrict__ b1,  const float* __restrict__ W2,
    const float* __restrict__ b2,  float* __restrict__ out)
{
    __shared__ float cc[NB][NV + 1];
    __shared__ float hfc[NB][NFC + 1];
    const int tid = threadIdx.x;
    for (int i = tid; i < NB * NV; i += 256) cc[i >> 4][i & 15] = cws[i];
    __syncthreads();

    float w1r[NV];
    #pragma unroll
    for (int q = 0; q < NV; q += 4) {
        float4 t4 = *(const float4*)(W1 + tid * NV + q);
        w1r[q] = t4.x; w1r[q+1] = t4.y; w1r[q+2] = t4.z; w1r[q+3] = t4.w;
    }
    const float bb = b1[tid];
    for (int b = 0; b < NB; ++b) {
        float sacc = bb;
        #pragma unroll
        for (int q = 0; q < NV; ++q) sacc = fmaf(cc[b][q], w1r[q], sacc);
        hfc[b][tid] = fmaxf(sacc, 0.f);
    }
    __syncthreads();

    for (int idx = tid; idx < NB * NC; idx += 256) {
        const int b = idx / NC, c = idx % NC;
        const float* w2r = W2 + c * NFC;
        float sacc = b2[c];
        #pragma unroll 4
        for (int f = 0; f < NFC; f += 4) {
            float4 wv = *(const float4*)(w2r + f);
            sacc = fmaf(hfc[b][f+0], wv.x, sacc);
            sacc = fmaf(hfc[b][f+1], wv.y, sacc);
            sacc = fmaf(hfc[b][f+2], wv.z, sacc);
            sacc = fmaf(hfc[b][f+3], wv.w, sacc);
        }
        out[idx] = sacc;
    }
}

extern "C" void kernel_launch(void* const* d_in, const int* in_sizes, int n_in,
                              void* d_out, int out_size, void* d_ws, size_t ws_size,
                              hipStream_t stream) {
    const float* x   = (const float*)d_in[0];
    const float* Wih = (const float*)d_in[1];
    const float* Whh = (const float*)d_in[2];
    const float* bih = (const float*)d_in[3];
    const float* bhh = (const float*)d_in[4];
    const float* Wp  = (const float*)d_in[5];
    const float* bp  = (const float*)d_in[6];
    const float* W1  = (const float*)d_in[7];
    const float* b1  = (const float*)d_in[8];
    const float* W2  = (const float*)d_in[9];
    const float* b2  = (const float*)d_in[10];
    float* out = (float*)d_out;
    float* cws = (float*)d_ws;  // concat scratch: 64*16 f32 = 4 KB

    gru_scan_kernel<<<dim3(512), dim3(256), 0, stream>>>(x, Wih, Whh, bih, bhh, Wp, bp, cws);
    fc_kernel<<<dim3(1), dim3(256), 0, stream>>>(cws, W1, b1, W2, b2, out);
}

// Round 10
// 239.499 us; speedup vs baseline: 1.1171x; 1.0926x over previous
//
#include <hip/hip_runtime.h>

#define NV  16
#define NB  64
#define NT  256
#define NH  128
#define NFC 256
#define NC  10

typedef _Float16 half8  __attribute__((ext_vector_type(8)));
typedef float    f32x4  __attribute__((ext_vector_type(4)));

// One workgroup = one variable v, FOUR batch rows, 4 waves (256 thr), 256 WGs
// -> 1 WG/CU on all 256 CUs, 1 wave/SIMD.
// Cost model (fits r2/r5/r6/r7/r9): per step per SIMD, MFMA pipe = 24 MFMAs x
// 19.4 = 466 cyc (invariant); LDS burst = waves x 4KB reads — 4 waves halves
// it vs the 8-wave configs (480 -> ~240); dup-4 keeps MFMA waste at 4x (r9's
// dup-8 was MFMA-bound at 932/SIMD).
// Wave w4 owns h-cols [w4*32, w4*32+32) = 6 tiles (3 gates x 2 col-ranges).
// B slots n hold h[row n&3] (dup-4): lane n = rb + 4q self-holds the full gh
// for (row rb, cols j_c = w4*32 + c*16 + m4*4 + q, c=0,1) in aa[g][c][q] ->
// zero cross-lane redistribution (r5/r6/r9-verified trick). 2 updates/lane.
// MFMA order: g0,g1 chains -> r/z trans (overlaps g2 pipe) -> g2 -> finish.
// C layout (verified r2): col(B slot) = lane&15, row = (lane>>4)*4 + reg.
// Activation algebra (prescaled, division-minimized, verified r2-r9):
//   r = rcp(1+exp2(srs)); a = exp2(szs); b = exp2(-ccs)
//   h' = [a(1-b) + h(1+b)] / [(1+a)(1+b)] ; num = fma(b, h-a, a+h)
// bih of r/z folded into MFMA C-init; n-gate bih outside the r-multiply.
__global__ __launch_bounds__(256, 1) void gru_scan_kernel(
    const float* __restrict__ x,   const float* __restrict__ Wih,
    const float* __restrict__ Whh, const float* __restrict__ bih,
    const float* __restrict__ bhh, const float* __restrict__ Wp,
    const float* __restrict__ bp,  float* __restrict__ concat_ws)
{
    __shared__ __align__(16) _Float16 frag[2][2048];  // 2 x 4KB: [kb*512 + slot*8]
    __shared__ float xT[NT][5];                       // x transposed, 4 rows padded
    __shared__ float pc[4][4];

    const int tid = threadIdx.x;
    const int w4  = tid >> 6;        // wave 0..3
    const int l   = tid & 63;
    const int n   = l & 15;          // B-slot / A-row index
    const int m4  = l >> 4;          // 0..3
    const int rb  = n & 3;           // this lane's batch row
    const int q   = n >> 2;          // C-reg selector (0..3)
    const int bid = blockIdx.x;
    const int v   = bid >> 4;        // variable
    const int b0  = (bid & 15) << 2; // batch base (4 rows)
    const int jc0 = (w4 << 5) + (m4 << 2) + q;        // col for c=0
    const int jc1 = jc0 + 16;                         // col for c=1

    constexpr float L2E = 1.44269504088896340736f;
    const float SCL0 = -L2E, SCL2 = 2.0f * L2E;

    // ---- stage x[v, b0+rr, :] into xT[t][rr] ----
    {
        const int rr = tid >> 6;          // 0..3
        const int t0 = (tid & 63) << 2;   // 0..252
        const float4 xv = *(const float4*)(x + (size_t)(v * NB + b0 + rr) * NT + t0);
        xT[t0][rr] = xv.x; xT[t0+1][rr] = xv.y; xT[t0+2][rr] = xv.z; xT[t0+3][rr] = xv.w;
    }
    // zero BOTH frag buffers (h0 = 0)
    ((int4*)frag)[tid]       = int4{0, 0, 0, 0};
    ((int4*)frag)[tid + 256] = int4{0, 0, 0, 0};

    // ---- preload PRESCALED Whh A-fragments for 6 tiles (g, c) ----
    // tile gate-rows: g*128 + w4*32 + c*16 + n; A[n][k = kb*32 + m4*8 + e]
    half8 afr[3][2][4];
    #pragma unroll
    for (int g = 0; g < 3; ++g) {
        const float sc = (g == 2) ? SCL2 : SCL0;
        #pragma unroll
        for (int c2 = 0; c2 < 2; ++c2) {
            #pragma unroll
            for (int kb = 0; kb < 4; ++kb) {
                const float* wpp = Whh
                    + (size_t)(v * 384 + g * 128 + (w4 << 5) + (c2 << 4) + n) * 128
                    + kb * 32 + m4 * 8;
                float4 lo = *(const float4*)wpp;
                float4 hi = *(const float4*)(wpp + 4);
                half8 hf;
                hf[0]=(_Float16)(sc*lo.x); hf[1]=(_Float16)(sc*lo.y);
                hf[2]=(_Float16)(sc*lo.z); hf[3]=(_Float16)(sc*lo.w);
                hf[4]=(_Float16)(sc*hi.x); hf[5]=(_Float16)(sc*hi.y);
                hf[6]=(_Float16)(sc*hi.z); hf[7]=(_Float16)(sc*hi.w);
                afr[g][c2][kb] = hf;
            }
        }
    }

    // MFMA C-init per tile (rows m4*4+reg of col-range (w4,c)):
    //   r/z: prescaled (bhh + bih); n: prescaled bhh only
    f32x4 cini[3][2];
    #pragma unroll
    for (int g = 0; g < 3; ++g) {
        const float sc = (g == 2) ? SCL2 : SCL0;
        #pragma unroll
        for (int c2 = 0; c2 < 2; ++c2) {
            #pragma unroll
            for (int reg = 0; reg < 4; ++reg) {
                const int i0 = v * 384 + g * 128 + (w4 << 5) + (c2 << 4) + (m4 << 2) + reg;
                float bsum = bhh[i0];
                if (g < 2) bsum += bih[i0];
                cini[g][c2][reg] = sc * bsum;
            }
        }
    }
    // handler params for cols jc0, jc1
    float wih2[3][2], bihn2[2], wpj2[2];
    #pragma unroll
    for (int c2 = 0; c2 < 2; ++c2) {
        const int ih = v * 384 + ((c2 == 0) ? jc0 : jc1);
        wih2[0][c2] = SCL0 * Wih[ih];
        wih2[1][c2] = SCL0 * Wih[ih + 128];
        wih2[2][c2] = SCL2 * Wih[ih + 256];
        bihn2[c2]   = SCL2 * bih[ih + 256];
        wpj2[c2]    = Wp[v * NH + ((c2 == 0) ? jc0 : jc1)];
    }

    float h_old[2] = {0.f, 0.f};

    // write base for (row rb, col j_c): halfs offset
    //   w4*512 + (rb + 4i + 16*(c*2 + (m4>>1)))*8 + (m4&1)*4 + q, i=0..3
    const int fwb0 = (w4 << 9) + (rb + 16 * ((m4 >> 1))) * 8 + ((m4 & 1) << 2) + q;
    const int fwb1 = fwb0 + 16 * 2 * 8;   // c=1: +16*2 slots-of-8
    const int rdoff = l * 8;

    __syncthreads();

    auto step = [&](const _Float16* __restrict__ fb, _Float16* __restrict__ fwb,
                    const float xr) {
        half8 bfr[4];
        #pragma unroll
        for (int kb = 0; kb < 4; ++kb)
            bfr[kb] = *(const half8*)(fb + kb * 512 + rdoff);

        // g0 and g1 chains first (both col-ranges)
        f32x4 a00 = __builtin_amdgcn_mfma_f32_16x16x32_f16(afr[0][0][0], bfr[0], cini[0][0], 0, 0, 0);
        f32x4 a01 = __builtin_amdgcn_mfma_f32_16x16x32_f16(afr[0][1][0], bfr[0], cini[0][1], 0, 0, 0);
        f32x4 a10 = __builtin_amdgcn_mfma_f32_16x16x32_f16(afr[1][0][0], bfr[0], cini[1][0], 0, 0, 0);
        f32x4 a11 = __builtin_amdgcn_mfma_f32_16x16x32_f16(afr[1][1][0], bfr[0], cini[1][1], 0, 0, 0);
        #pragma unroll
        for (int kb = 1; kb < 4; ++kb) {
            a00 = __builtin_amdgcn_mfma_f32_16x16x32_f16(afr[0][0][kb], bfr[kb], a00, 0, 0, 0);
            a01 = __builtin_amdgcn_mfma_f32_16x16x32_f16(afr[0][1][kb], bfr[kb], a01, 0, 0, 0);
            a10 = __builtin_amdgcn_mfma_f32_16x16x32_f16(afr[1][0][kb], bfr[kb], a10, 0, 0, 0);
            a11 = __builtin_amdgcn_mfma_f32_16x16x32_f16(afr[1][1][kb], bfr[kb], a11, 0, 0, 0);
        }
        // g2 chains issued next; r/z trans below overlaps the g2 pipe
        f32x4 a20 = __builtin_amdgcn_mfma_f32_16x16x32_f16(afr[2][0][0], bfr[0], cini[2][0], 0, 0, 0);
        f32x4 a21 = __builtin_amdgcn_mfma_f32_16x16x32_f16(afr[2][1][0], bfr[0], cini[2][1], 0, 0, 0);
        #pragma unroll
        for (int kb = 1; kb < 4; ++kb) {
            a20 = __builtin_amdgcn_mfma_f32_16x16x32_f16(afr[2][0][kb], bfr[kb], a20, 0, 0, 0);
            a21 = __builtin_amdgcn_mfma_f32_16x16x32_f16(afr[2][1][kb], bfr[kb], a21, 0, 0, 0);
        }

        // local pick via q-cndmask (zero cross-lane); r/z act for both cols
        const bool q1 = (q & 1) != 0, q2 = (q & 2) != 0;
        float rg[2], av[2];
        #pragma unroll
        for (int c2 = 0; c2 < 2; ++c2) {
            const f32x4& t0 = (c2 == 0) ? a00 : a01;
            const f32x4& t1 = (c2 == 0) ? a10 : a11;
            const float g0 = q2 ? (q1 ? t0[3] : t0[2]) : (q1 ? t0[1] : t0[0]);
            const float g1 = q2 ? (q1 ? t1[3] : t1[2]) : (q1 ? t1[1] : t1[0]);
            const float xrw = xr;
            const float srs = fmaf(xrw, wih2[0][c2], g0);
            const float szs = fmaf(xrw, wih2[1][c2], g1);
            rg[c2] = __builtin_amdgcn_rcpf(1.f + __builtin_amdgcn_exp2f(srs));
            av[c2] = __builtin_amdgcn_exp2f(szs);
        }
        // n-gate + update for both cols
        _Float16 hv[2];
        #pragma unroll
        for (int c2 = 0; c2 < 2; ++c2) {
            const f32x4& t2 = (c2 == 0) ? a20 : a21;
            const float g2v = q2 ? (q1 ? t2[3] : t2[2]) : (q1 ? t2[1] : t2[0]);
            const float gns = fmaf(xr, wih2[2][c2], bihn2[c2]);
            const float ccs = fmaf(rg[c2], g2v, gns);
            const float b   = __builtin_amdgcn_exp2f(-ccs);
            const float a   = av[c2];
            const float h   = h_old[c2];
            const float num = fmaf(b, h - a, a + h);   // a(1-b) + h(1+b)
            const float den = (1.f + a) * (1.f + b);
            const float hn  = num * __builtin_amdgcn_rcpf(den);
            h_old[c2] = hn;
            hv[c2] = (_Float16)hn;
        }
        #pragma unroll
        for (int i = 0; i < 4; ++i) {
            fwb[fwb0 + i * 32] = hv[0];   // c=0, dup slots rb+4i (+4 slots * 8 halfs)
            fwb[fwb1 + i * 32] = hv[1];   // c=1
        }
        __syncthreads();
    };

    for (int t = 0; t < NT; t += 2) {
        const float xa = xT[t][rb];
        const float xb = xT[t + 1][rb];
        step(&frag[0][0], &frag[1][0], xa);
        step(&frag[1][0], &frag[0][0], xb);
    }

    // ---- epilogue: concat[b0+rb][v] = sum_j h[rb][j]*Wp[v][j] + bp[v] ----
    float partial = h_old[0] * wpj2[0] + h_old[1] * wpj2[1];
    partial += __shfl_xor(partial, 4, 64);    // over q low bit
    partial += __shfl_xor(partial, 8, 64);    // over q high bit
    partial += __shfl_xor(partial, 16, 64);   // over m4
    partial += __shfl_xor(partial, 32, 64);
    if (l < 4) pc[w4][l] = partial;
    __syncthreads();
    if (tid < 4) {
        float acc = bp[v];
        #pragma unroll
        for (int ww = 0; ww < 4; ++ww) acc += pc[ww][tid];
        concat_ws[(b0 + tid) * NV + v] = acc;
    }
}

// FC head: concat[64][16] -> relu(W1) -> W2 -> out[64][10]. One small block.
__global__ __launch_bounds__(256, 1) void fc_kernel(
    const float* __restrict__ cws, const float* __restrict__ W1,
    const float* __restrict__ b1,  const float* __restrict__ W2,
    const float* __restrict__ b2,  float* __restrict__ out)
{
    __shared__ float cc[NB][NV + 1];
    __shared__ float hfc[NB][NFC + 1];
    const int tid = threadIdx.x;
    for (int i = tid; i < NB * NV; i += 256) cc[i >> 4][i & 15] = cws[i];
    __syncthreads();

    float w1r[NV];
    #pragma unroll
    for (int q = 0; q < NV; q += 4) {
        float4 t4 = *(const float4*)(W1 + tid * NV + q);
        w1r[q] = t4.x; w1r[q+1] = t4.y; w1r[q+2] = t4.z; w1r[q+3] = t4.w;
    }
    const float bb = b1[tid];
    for (int b = 0; b < NB; ++b) {
        float sacc = bb;
        #pragma unroll
        for (int q = 0; q < NV; ++q) sacc = fmaf(cc[b][q], w1r[q], sacc);
        hfc[b][tid] = fmaxf(sacc, 0.f);
    }
    __syncthreads();

    for (int idx = tid; idx < NB * NC; idx += 256) {
        const int b = idx / NC, c = idx % NC;
        const float* w2r = W2 + c * NFC;
        float sacc = b2[c];
        #pragma unroll 4
        for (int f = 0; f < NFC; f += 4) {
            float4 wv = *(const float4*)(w2r + f);
            sacc = fmaf(hfc[b][f+0], wv.x, sacc);
            sacc = fmaf(hfc[b][f+1], wv.y, sacc);
            sacc = fmaf(hfc[b][f+2], wv.z, sacc);
            sacc = fmaf(hfc[b][f+3], wv.w, sacc);
        }
        out[idx] = sacc;
    }
}

extern "C" void kernel_launch(void* const* d_in, const int* in_sizes, int n_in,
                              void* d_out, int out_size, void* d_ws, size_t ws_size,
                              hipStream_t stream) {
    const float* x   = (const float*)d_in[0];
    const float* Wih = (const float*)d_in[1];
    const float* Whh = (const float*)d_in[2];
    const float* bih = (const float*)d_in[3];
    const float* bhh = (const float*)d_in[4];
    const float* Wp  = (const float*)d_in[5];
    const float* bp  = (const float*)d_in[6];
    const float* W1  = (const float*)d_in[7];
    const float* b1  = (const float*)d_in[8];
    const float* W2  = (const float*)d_in[9];
    const float* b2  = (const float*)d_in[10];
    float* out = (float*)d_out;
    float* cws = (float*)d_ws;  // concat scratch: 64*16 f32 = 4 KB

    gru_scan_kernel<<<dim3(256), dim3(256), 0, stream>>>(x, Wih, Whh, bih, bhh, Wp, bp, cws);
    fc_kernel<<<dim3(1), dim3(256), 0, stream>>>(cws, W1, b1, W2, b2, out);
}